// Round 6
// baseline (106.575 us; speedup 1.0000x reference)
//
#include <hip/hip_runtime.h>
#include <cstdint>
#include <cstddef>

#define N_PATH 14
#define NEG_SLOPE 0.2f
#define BINW 128

using u16 = unsigned short;
using u32 = unsigned int;
typedef __attribute__((ext_vector_type(4))) float f32x4;
typedef __attribute__((ext_vector_type(8))) short bf16x8;

__device__ __forceinline__ float lrelu(float v) { return v > 0.f ? v : NEG_SLOPE * v; }
__device__ __forceinline__ u16 f2bf(float f) {
    union { float f; u32 u; } c; c.f = f;
    return (u16)((c.u + 0x7FFFu + ((c.u >> 16) & 1u)) >> 16);
}
__device__ __forceinline__ float bf2f(u16 v) {
    union { u32 u; float f; } c; c.u = ((u32)v) << 16; return c.f;
}

// ------------------------------------------------------------------
// Init: mapB/mapC = -1; zero cnt/deg2/deg1
// ------------------------------------------------------------------
__global__ void k_init(int* __restrict__ mapBC, int nMap,
                       u32* __restrict__ z, int nZ)
{
    int stride = gridDim.x * blockDim.x;
    int i0 = blockIdx.x * blockDim.x + threadIdx.x;
    for (int i = i0; i < nMap; i += stride) mapBC[i] = -1;
    for (int i = i0; i < nZ; i += stride) z[i] = 0;
}

// ------------------------------------------------------------------
// Frontier building. cnt[0]=nB, cnt[1]=nC
// ------------------------------------------------------------------
__global__ void k_build2(const int* __restrict__ esrc, const int* __restrict__ edst,
                         int E, int Nn,
                         int* __restrict__ mapB, int* __restrict__ listB,
                         int* __restrict__ cnt,
                         int* __restrict__ deg2, int* __restrict__ e2bin,
                         int capB)
{
    int e = blockIdx.x * blockDim.x + threadIdx.x;
    int ET = E + Nn;
    if (e >= ET) return;
    int s, d;
    if (e < E) { s = esrc[e]; d = edst[e]; } else { s = e - E; d = s; }
    if (d >= N_PATH) return;
    int slot = atomicAdd(&deg2[d], 1);
    if (slot < BINW) e2bin[d * BINW + slot] = s;
    int old = atomicCAS(&mapB[s], -1, -2);
    if (old == -1) {
        int idx = atomicAdd(&cnt[0], 1);
        if (idx < capB) listB[idx] = s;
        mapB[s] = idx;
    }
}

__global__ void k_build1(const int* __restrict__ esrc, const int* __restrict__ edst,
                         int E, int Nn,
                         const int* __restrict__ mapB,
                         int* __restrict__ mapC, int* __restrict__ listC,
                         int* __restrict__ cnt,
                         int* __restrict__ deg1, int* __restrict__ e1bin,
                         int capB, int capC)
{
    int e = blockIdx.x * blockDim.x + threadIdx.x;
    int ET = E + Nn;
    if (e >= ET) return;
    int s, d;
    if (e < E) { s = esrc[e]; d = edst[e]; } else { s = e - E; d = s; }
    int b = mapB[d];
    if (b < 0 || b >= capB) return;
    int slot = atomicAdd(&deg1[b], 1);
    if (slot < BINW) e1bin[b * BINW + slot] = s;
    int old = atomicCAS(&mapC[s], -1, -2);
    if (old == -1) {
        int idx = atomicAdd(&cnt[1], 1);
        if (idx < capC) listC[idx] = s;
        mapC[s] = idx;
    }
}

// ------------------------------------------------------------------
// Gather x rows (listC) -> compact bf16 Abf [capC][768]; also compute
// pre-clamped listBinC (B-row -> C-row) in the extra block.
// ------------------------------------------------------------------
__global__ void k_gatherA(const float* __restrict__ x,
                          const int* __restrict__ listC, const int* __restrict__ listB,
                          const int* __restrict__ mapC, const int* __restrict__ cnt,
                          u16* __restrict__ Abf, int* __restrict__ listBinC,
                          int capB, int capC)
{
    int bid = blockIdx.x;
    int t = threadIdx.x;
    if (bid == capC) {
        int nB = cnt[0]; if (nB > capB) nB = capB;
        for (int i = t; i < capB; i += 192) {
            int v = 0;
            if (i < nB) {
                v = mapC[listB[i]];
                if (v < 0) v = 0;
                if (v >= capC) v = capC - 1;
            }
            listBinC[i] = v;
        }
        return;
    }
    int nC = cnt[1]; if (nC > capC) nC = capC;
    if (bid >= nC) return;
    int g = listC[bid];
    float4 v = *reinterpret_cast<const float4*>(x + (size_t)g * 768 + t * 4);
    uint2 o;
    o.x = (u32)f2bf(v.x) | ((u32)f2bf(v.y) << 16);
    o.y = (u32)f2bf(v.z) | ((u32)f2bf(v.w) << 16);
    *reinterpret_cast<uint2*>(Abf + (size_t)bid * 768 + t * 4) = o;
}

// ------------------------------------------------------------------
// Weight-stationary MFMA GEMM core.
// Block owns BN cols x KD of K; stages W[k][n0..n0+BN) (f32, k-major)
// once into LDS as bf16 [BN][KD] with 16B-chunk XOR swizzle. Then loops
// row-tiles; A fragments read direct global->reg (bf16 compact,
// L2-resident), double-buffered; no syncthreads in the K loop.
// 4 waves arranged (4/NWN) x NWN; wave = (MF*16) rows x 16 cols.
// MODE: 2 = bf16 store (+bias), 0 = f32 store (no bias).
// NOTE: A must already point at the K-window matching W (caller offsets).
// ------------------------------------------------------------------
template<int MF, int NWN, int KD, int MODE>
__device__ __forceinline__
void gemm_core(const u16* __restrict__ A, int lda,
               const int* __restrict__ gather,
               const float* __restrict__ W, int ldw,
               const float* __restrict__ bias,
               void* __restrict__ Cout, int ldc,
               int M, int n0, int rt0, int rtStep,
               u16* __restrict__ Bs)
{
    constexpr int WM = MF * 16;
    constexpr int BM = (4 / NWN) * WM;
    constexpr int BN = NWN * 16;
    constexpr int NSTEP = KD / 64;
    constexpr int NQ = BN / 4;

    if (rt0 * BM >= M) return;

    int t = threadIdx.x;
    int lane = t & 63, wave = t >> 6;
    int wr = wave / NWN, wc = wave % NWN;
    int lrow = lane & 15, lhi = lane >> 4;

    // stage W strip -> LDS (once per block)
    for (int idx = t; idx < KD * NQ; idx += 256) {
        int k = idx / NQ;
        int n = (idx % NQ) * 4;
        float4 wv = *reinterpret_cast<const float4*>(W + (size_t)k * ldw + n0 + n);
        int c = k >> 3, kl = k & 7;
        float wa[4] = {wv.x, wv.y, wv.z, wv.w};
        #pragma unroll
        for (int j = 0; j < 4; ++j) {
            int nn = n + j;
            Bs[nn * KD + (((c ^ (nn & 7)) << 3) | kl)] = f2bf(wa[j]);
        }
    }
    __syncthreads();

    int bcol = wc * 16 + lrow;
    int bbase = bcol * KD;
    int bx7 = bcol & 7;

    for (int m0 = rt0 * BM; m0 < M; m0 += rtStep * BM) {
        int arow[MF];
        #pragma unroll
        for (int mi = 0; mi < MF; ++mi) {
            int r = m0 + wr * WM + mi * 16 + lrow;
            if (r >= M) r = M - 1;
            arow[mi] = gather ? gather[r] : r;
        }
        f32x4 acc[MF];
        #pragma unroll
        for (int mi = 0; mi < MF; ++mi) acc[mi] = (f32x4){0.f, 0.f, 0.f, 0.f};

        uint4 abuf[2][MF][2];
        #pragma unroll
        for (int mi = 0; mi < MF; ++mi)
            #pragma unroll
            for (int ks = 0; ks < 2; ++ks)
                abuf[0][mi][ks] = *reinterpret_cast<const uint4*>(
                    A + (size_t)arow[mi] * lda + ks * 32 + lhi * 8);

        #pragma unroll
        for (int step = 0; step < NSTEP; ++step) {
            int cur = step & 1, nxt = cur ^ 1;
            if (step + 1 < NSTEP) {
                int kb = (step + 1) * 64;
                #pragma unroll
                for (int mi = 0; mi < MF; ++mi)
                    #pragma unroll
                    for (int ks = 0; ks < 2; ++ks)
                        abuf[nxt][mi][ks] = *reinterpret_cast<const uint4*>(
                            A + (size_t)arow[mi] * lda + kb + ks * 32 + lhi * 8);
            }
            #pragma unroll
            for (int ks = 0; ks < 2; ++ks) {
                int c = step * 8 + ks * 4 + lhi;
                bf16x8 b = *reinterpret_cast<const bf16x8*>(&Bs[bbase + ((c ^ bx7) << 3)]);
                #pragma unroll
                for (int mi = 0; mi < MF; ++mi)
                    acc[mi] = __builtin_amdgcn_mfma_f32_16x16x32_bf16(
                        *reinterpret_cast<bf16x8*>(&abuf[cur][mi][ks]), b, acc[mi], 0, 0, 0);
            }
        }

        int gc = n0 + wc * 16 + lrow;
        float bv = 0.f;
        if (MODE == 2) bv = bias[gc];
        #pragma unroll
        for (int mi = 0; mi < MF; ++mi)
            #pragma unroll
            for (int j = 0; j < 4; ++j) {
                int gr = m0 + wr * WM + mi * 16 + lhi * 4 + j;
                if (gr < M) {
                    float v = acc[mi][j] + bv;
                    if (MODE == 2) ((u16*)Cout)[(size_t)gr * ldc + gc] = f2bf(v);
                    else           ((float*)Cout)[(size_t)gr * ldc + gc] = v;
                }
            }
    }
}

// Layer-1: XL1' = bf16(Abf@Wl1 + bl1), XR1' = bf16(Abf[listBinC]@Wr1 + br1)
__global__ __launch_bounds__(256, 3)
void k_gemm1(const u16* __restrict__ Abf, const int* __restrict__ listBinC,
             const float* __restrict__ Wl1, const float* __restrict__ Wr1,
             const float* __restrict__ bl1, const float* __restrict__ br1,
             u16* __restrict__ XL1, u16* __restrict__ XR1,
             const int* __restrict__ cnt, int capC, int capB)
{
    __shared__ __align__(16) u16 Bs[32 * 768];
    int bid = blockIdx.x;
    if (bid < 192) {
        int nC = cnt[1]; if (nC > capC) nC = capC;
        gemm_core<4, 2, 768, 2>(Abf, 768, nullptr, Wl1, 3072, bl1,
                                XL1, 3072, nC, (bid % 96) * 32, bid / 96, 2, Bs);
    } else {
        bid -= 192;
        int nB = cnt[0]; if (nB > capB) nB = capB;
        gemm_core<4, 2, 768, 2>(Abf, 768, listBinC, Wr1, 3072, br1,
                                XR1, 3072, nB, bid * 32, 0, 1, Bs);
    }
}

// Layer-2: XLR2part[z] = H1bf[:, z*1536:(z+1)*1536] @ [Wl2|Wr2][z-half]
// (f32 store, no bias). FIX vs round 5: A base offset by z*1536 so the
// A K-window matches the staged W K-half.
__global__ __launch_bounds__(256, 3)
void k_gemm2(const u16* __restrict__ H1bf,
             const float* __restrict__ Wl2, const float* __restrict__ Wr2,
             float* __restrict__ XLR2,
             const int* __restrict__ cnt, int capB)
{
    __shared__ __align__(16) u16 Bs[16 * 1536];
    int nB = cnt[0]; if (nB > capB) nB = capB;
    int z = blockIdx.z;
    int n0 = blockIdx.x * 16;              // global col in [0,1536)
    bool hi = n0 >= 768;
    const float* Wp = (hi ? Wr2 : Wl2) + (size_t)z * 1536 * 768 - (hi ? 768 : 0);
    float* Cp = XLR2 + (size_t)z * capB * 1536;
    gemm_core<2, 1, 1536, 0>(H1bf + (size_t)z * 1536, 3072, nullptr, Wp, 768,
                             nullptr, Cp, 1536, nB, n0, 0, 1, Bs);
}

// ------------------------------------------------------------------
// Fused layer-1 edge phase: one block per B node, 4 waves = 4 heads.
// ------------------------------------------------------------------
__global__ __launch_bounds__(256)
void k_fused1(const u16* __restrict__ XL1, const u16* __restrict__ XR1,
              const float* __restrict__ att1, const float* __restrict__ bias1,
              const int* __restrict__ mapC,
              const int* __restrict__ deg1, const int* __restrict__ e1bin,
              u16* __restrict__ H1bf,
              const int* __restrict__ cnt, int capB, int capC)
{
    __shared__ int sIdx[BINW];
    int b = blockIdx.x;
    int nB = cnt[0]; if (nB > capB) nB = capB;
    if (b >= nB) return;
    int t = threadIdx.x;
    int n = deg1[b]; if (n > BINW) n = BINW;
    if (t < n) {
        int c = mapC[e1bin[b * BINW + t]];
        if (c < 0) c = 0; if (c >= capC) c = capC - 1;
        sIdx[t] = c;
    }
    __syncthreads();

    int base = t * 12;
    float xr[12], av[12];
    {
        const u16* p = XR1 + (size_t)b * 3072 + base;
        uint2 q0 = *reinterpret_cast<const uint2*>(p);
        uint2 q1 = *reinterpret_cast<const uint2*>(p + 4);
        uint2 q2 = *reinterpret_cast<const uint2*>(p + 8);
        u32 w[6] = {q0.x, q0.y, q1.x, q1.y, q2.x, q2.y};
        #pragma unroll
        for (int j = 0; j < 6; ++j) {
            xr[2*j]   = bf2f((u16)(w[j] & 0xFFFF));
            xr[2*j+1] = bf2f((u16)(w[j] >> 16));
        }
        float4 a0 = *reinterpret_cast<const float4*>(att1 + base);
        float4 a1 = *reinterpret_cast<const float4*>(att1 + base + 4);
        float4 a2 = *reinterpret_cast<const float4*>(att1 + base + 8);
        av[0]=a0.x; av[1]=a0.y; av[2]=a0.z; av[3]=a0.w;
        av[4]=a1.x; av[5]=a1.y; av[6]=a1.z; av[7]=a1.w;
        av[8]=a2.x; av[9]=a2.y; av[10]=a2.z; av[11]=a2.w;
    }

    float acc[12];
    #pragma unroll
    for (int j = 0; j < 12; ++j) acc[j] = 0.f;
    float sumex = 0.f;

    uint2 q0, q1, q2;
    if (n > 0) {
        const u16* p = XL1 + (size_t)sIdx[0] * 3072 + base;
        q0 = *reinterpret_cast<const uint2*>(p);
        q1 = *reinterpret_cast<const uint2*>(p + 4);
        q2 = *reinterpret_cast<const uint2*>(p + 8);
    }
    for (int i = 0; i < n; ++i) {
        uint2 r0 = q0, r1 = q1, r2 = q2;
        if (i + 1 < n) {
            const u16* p = XL1 + (size_t)sIdx[i + 1] * 3072 + base;
            q0 = *reinterpret_cast<const uint2*>(p);
            q1 = *reinterpret_cast<const uint2*>(p + 4);
            q2 = *reinterpret_cast<const uint2*>(p + 8);
        }
        float xl[12];
        u32 w[6] = {r0.x, r0.y, r1.x, r1.y, r2.x, r2.y};
        #pragma unroll
        for (int j = 0; j < 6; ++j) {
            xl[2*j]   = bf2f((u16)(w[j] & 0xFFFF));
            xl[2*j+1] = bf2f((u16)(w[j] >> 16));
        }
        float pa = 0.f;
        #pragma unroll
        for (int j = 0; j < 12; ++j)
            pa = fmaf(av[j], lrelu(xl[j] + xr[j]), pa);
        #pragma unroll
        for (int off = 32; off > 0; off >>= 1) pa += __shfl_xor(pa, off);
        float ex = expf(pa);
        sumex += ex;
        #pragma unroll
        for (int j = 0; j < 12; ++j) acc[j] = fmaf(ex, xl[j], acc[j]);
    }

    float inv = 1.f / (sumex + 1e-16f);
    u32 o[6];
    #pragma unroll
    for (int j = 0; j < 6; ++j) {
        float v0 = acc[2*j]   * inv + bias1[base + 2*j];
        float v1 = acc[2*j+1] * inv + bias1[base + 2*j+1];
        v0 = v0 > 0.f ? v0 : 0.f;
        v1 = v1 > 0.f ? v1 : 0.f;
        o[j] = (u32)f2bf(v0) | ((u32)f2bf(v1) << 16);
    }
    u16* q = H1bf + (size_t)b * 3072 + base;
    uint2 s0; s0.x = o[0]; s0.y = o[1];
    uint2 s1; s1.x = o[2]; s1.y = o[3];
    uint2 s2; s2.x = o[4]; s2.y = o[5];
    *reinterpret_cast<uint2*>(q)     = s0;
    *reinterpret_cast<uint2*>(q + 4) = s1;
    *reinterpret_cast<uint2*>(q + 8) = s2;
}

// ------------------------------------------------------------------
// Fused layer-2 edge phase: one block per pathology node, 4 waves split
// edges, LDS combine. Sums the two K-half partials + biases. Writes d_out.
// ------------------------------------------------------------------
__global__ __launch_bounds__(256)
void k_fused2(const float* __restrict__ XLR2,
              const float* __restrict__ att2, const float* __restrict__ bias2,
              const float* __restrict__ bl2, const float* __restrict__ br2,
              const int* __restrict__ mapB,
              const int* __restrict__ deg2, const int* __restrict__ e2bin,
              float* __restrict__ out, int capB)
{
    __shared__ int sIdx[BINW];
    __shared__ float sAcc[4][768];
    __shared__ float sSum[4];
    const int PART = capB * 1536;
    int a = blockIdx.x;
    int t = threadIdx.x;
    int wv = t >> 6, lane = t & 63;
    int n = deg2[a]; if (n > BINW) n = BINW;
    if (t < n) {
        int bs = mapB[e2bin[a * BINW + t]];
        if (bs < 0) bs = 0; if (bs >= capB) bs = capB - 1;
        sIdx[t] = bs;
    }
    __syncthreads();

    int base = lane * 12;
    int bd = mapB[a];
    if (bd < 0) bd = 0; if (bd >= capB) bd = capB - 1;

    float xr[12], av[12], blv[12];
    {
        const float* p = XLR2 + (size_t)bd * 1536 + 768 + base;
        #pragma unroll
        for (int j = 0; j < 12; ++j) xr[j] = p[j] + p[PART + j] + br2[base + j];
        #pragma unroll
        for (int j = 0; j < 12; ++j) { av[j] = att2[base + j]; blv[j] = bl2[base + j]; }
    }

    float acc[12];
    #pragma unroll
    for (int j = 0; j < 12; ++j) acc[j] = 0.f;
    float sumex = 0.f;

    for (int i = wv; i < n; i += 4) {
        int bs = sIdx[i];
        const float* p = XLR2 + (size_t)bs * 1536 + base;
        float xl[12];
        #pragma unroll
        for (int j = 0; j < 12; ++j) xl[j] = p[j] + p[PART + j] + blv[j];
        float pa = 0.f;
        #pragma unroll
        for (int j = 0; j < 12; ++j)
            pa = fmaf(av[j], lrelu(xl[j] + xr[j]), pa);
        #pragma unroll
        for (int off = 32; off > 0; off >>= 1) pa += __shfl_xor(pa, off);
        float ex = expf(pa);
        sumex += ex;
        #pragma unroll
        for (int j = 0; j < 12; ++j) acc[j] = fmaf(ex, xl[j], acc[j]);
    }

    if (lane == 0) sSum[wv] = sumex;
    #pragma unroll
    for (int j = 0; j < 12; ++j) sAcc[wv][base + j] = acc[j];
    __syncthreads();

    float tot = sSum[0] + sSum[1] + sSum[2] + sSum[3];
    float inv = 1.f / (tot + 1e-16f);
    for (int c = t; c < 768; c += 256) {
        float s = sAcc[0][c] + sAcc[1][c] + sAcc[2][c] + sAcc[3][c];
        out[(size_t)a * 768 + c] = s * inv + bias2[c];
    }
}

// ------------------------------------------------------------------
// Host side
// ------------------------------------------------------------------
struct Lay {
    size_t mapB, mapC;
    size_t zbase, zbytes;
    size_t cnt, deg2, deg1;
    size_t listB, listC, listBinC, e1bin, e2bin;
    size_t Abf, XL1, XR1, H1bf, XLR2;
    size_t total;
};

static Lay makeLayout(int Nn, int cB, int cC)
{
    Lay L{};
    size_t off = 0;
    auto take = [&](size_t bytes) { size_t o = (off + 255) & ~(size_t)255; off = o + bytes; return o; };
    L.mapB = take((size_t)2 * Nn * 4);
    L.mapC = L.mapB + (size_t)Nn * 4;
    size_t zo = 0;
    size_t cntO  = zo; zo += 64;
    size_t deg2O = zo; zo += 64 * 4;
    size_t deg1O = zo; zo += (size_t)cB * 4;
    L.zbase = take(zo); L.zbytes = zo;
    L.cnt  = L.zbase + cntO;
    L.deg2 = L.zbase + deg2O;
    L.deg1 = L.zbase + deg1O;
    L.listB    = take((size_t)cB * 4);
    L.listC    = take((size_t)cC * 4);
    L.listBinC = take((size_t)cB * 4);
    L.e1bin = take((size_t)cB * BINW * 4);
    L.e2bin = take((size_t)16 * BINW * 4);
    L.Abf  = take((size_t)cC * 768 * 2);
    L.XL1  = take((size_t)cC * 3072 * 2);
    L.XR1  = take((size_t)cB * 3072 * 2);
    L.H1bf = take((size_t)cB * 3072 * 2);
    L.XLR2 = take((size_t)2 * cB * 1536 * 4);
    L.total = off;
    return L;
}

extern "C" void kernel_launch(void* const* d_in, const int* in_sizes, int n_in,
                              void* d_out, int out_size, void* d_ws, size_t ws_size,
                              hipStream_t stream)
{
    const float* x     = (const float*)d_in[0];
    const int*   ei    = (const int*)  d_in[1];
    const float* Wl1   = (const float*)d_in[2];
    const float* bl1   = (const float*)d_in[3];
    const float* Wr1   = (const float*)d_in[4];
    const float* br1   = (const float*)d_in[5];
    const float* att1  = (const float*)d_in[6];
    const float* bias1 = (const float*)d_in[7];
    const float* Wl2   = (const float*)d_in[8];
    const float* bl2   = (const float*)d_in[9];
    const float* Wr2   = (const float*)d_in[10];
    const float* br2   = (const float*)d_in[11];
    const float* att2  = (const float*)d_in[12];
    const float* bias2 = (const float*)d_in[13];
    float* out = (float*)d_out;

    int Nn = in_sizes[0] / 768;
    int E  = in_sizes[1] / 2;
    const int* esrc = ei;
    const int* edst = ei + E;
    int ET = E + Nn;

    // expected actual sizes: B~99, C~650
    static const int tiers[2][2] = { {256, 1024}, {128, 768} };
    int capB = tiers[1][0], capC = tiers[1][1];
    Lay L = makeLayout(Nn, capB, capC);
    for (int t = 0; t < 2; ++t) {
        Lay cand = makeLayout(Nn, tiers[t][0], tiers[t][1]);
        if (cand.total <= ws_size) { capB = tiers[t][0]; capC = tiers[t][1]; L = cand; break; }
    }

    char* ws = (char*)d_ws;
    int*   mapB     = (int*)  (ws + L.mapB);
    int*   mapC     = (int*)  (ws + L.mapC);
    int*   cnt      = (int*)  (ws + L.cnt);
    int*   deg2     = (int*)  (ws + L.deg2);
    int*   deg1     = (int*)  (ws + L.deg1);
    int*   listB    = (int*)  (ws + L.listB);
    int*   listC    = (int*)  (ws + L.listC);
    int*   listBinC = (int*)  (ws + L.listBinC);
    int*   e1bin    = (int*)  (ws + L.e1bin);
    int*   e2bin    = (int*)  (ws + L.e2bin);
    u16*   Abf      = (u16*)  (ws + L.Abf);
    u16*   XL1      = (u16*)  (ws + L.XL1);
    u16*   XR1      = (u16*)  (ws + L.XR1);
    u16*   H1bf     = (u16*)  (ws + L.H1bf);
    float* XLR2     = (float*)(ws + L.XLR2);

    k_init<<<256, 256, 0, stream>>>((int*)(ws + L.mapB), 2 * Nn,
                                    (u32*)(ws + L.zbase), (int)(L.zbytes / 4));

    int bgrid = (ET + 255) / 256;
    k_build2<<<bgrid, 256, 0, stream>>>(esrc, edst, E, Nn, mapB, listB, cnt,
                                        deg2, e2bin, capB);
    k_build1<<<bgrid, 256, 0, stream>>>(esrc, edst, E, Nn, mapB, mapC, listC, cnt,
                                        deg1, e1bin, capB, capC);

    k_gatherA<<<capC + 1, 192, 0, stream>>>(x, listC, listB, mapC, cnt,
                                            Abf, listBinC, capB, capC);

    k_gemm1<<<288, 256, 0, stream>>>(Abf, listBinC, Wl1, Wr1, bl1, br1,
                                     XL1, XR1, cnt, capC, capB);

    k_fused1<<<capB, 256, 0, stream>>>(XL1, XR1, att1, bias1, mapC, deg1, e1bin,
                                       H1bf, cnt, capB, capC);

    k_gemm2<<<dim3(96, 1, 2), 256, 0, stream>>>(H1bf, Wl2, Wr2, XLR2, cnt, capB);

    k_fused2<<<N_PATH, 256, 0, stream>>>(XLR2, att2, bias2, bl2, br2, mapB,
                                         deg2, e2bin, out, capB);
}

// Round 7
// 87.540 us; speedup vs baseline: 1.2174x; 1.2174x over previous
//
#include <hip/hip_runtime.h>
#include <cstdint>
#include <cstddef>

#define N_PATH 14
#define NEG_SLOPE 0.2f
#define BINW 128
#define NZ2 4          // layer-2 K-split (partial buffers)

using u16 = unsigned short;
using u32 = unsigned int;
typedef __attribute__((ext_vector_type(4))) float f32x4;
typedef __attribute__((ext_vector_type(8))) short bf16x8;

__device__ __forceinline__ float lrelu(float v) { return v > 0.f ? v : NEG_SLOPE * v; }
__device__ __forceinline__ u16 f2bf(float f) {
    union { float f; u32 u; } c; c.f = f;
    return (u16)((c.u + 0x7FFFu + ((c.u >> 16) & 1u)) >> 16);
}
__device__ __forceinline__ float bf2f(u16 v) {
    union { u32 u; float f; } c; c.u = ((u32)v) << 16; return c.f;
}

// ------------------------------------------------------------------
// Init: mapB/mapC = -1; zero cnt/deg2/deg1
// ------------------------------------------------------------------
__global__ void k_init(int* __restrict__ mapBC, int nMap,
                       u32* __restrict__ z, int nZ)
{
    int stride = gridDim.x * blockDim.x;
    int i0 = blockIdx.x * blockDim.x + threadIdx.x;
    for (int i = i0; i < nMap; i += stride) mapBC[i] = -1;
    for (int i = i0; i < nZ; i += stride) z[i] = 0;
}

// ------------------------------------------------------------------
// Frontier building. cnt[0]=nB, cnt[1]=nC
// ------------------------------------------------------------------
__global__ void k_build2(const int* __restrict__ esrc, const int* __restrict__ edst,
                         int E, int Nn,
                         int* __restrict__ mapB, int* __restrict__ listB,
                         int* __restrict__ cnt,
                         int* __restrict__ deg2, int* __restrict__ e2bin,
                         int capB)
{
    int e = blockIdx.x * blockDim.x + threadIdx.x;
    int ET = E + Nn;
    if (e >= ET) return;
    int s, d;
    if (e < E) { s = esrc[e]; d = edst[e]; } else { s = e - E; d = s; }
    if (d >= N_PATH) return;
    int slot = atomicAdd(&deg2[d], 1);
    if (slot < BINW) e2bin[d * BINW + slot] = s;
    int old = atomicCAS(&mapB[s], -1, -2);
    if (old == -1) {
        int idx = atomicAdd(&cnt[0], 1);
        if (idx < capB) listB[idx] = s;
        mapB[s] = idx;
    }
}

__global__ void k_build1(const int* __restrict__ esrc, const int* __restrict__ edst,
                         int E, int Nn,
                         const int* __restrict__ mapB,
                         int* __restrict__ mapC, int* __restrict__ listC,
                         int* __restrict__ cnt,
                         int* __restrict__ deg1, int* __restrict__ e1bin,
                         int capB, int capC)
{
    int e = blockIdx.x * blockDim.x + threadIdx.x;
    int ET = E + Nn;
    if (e >= ET) return;
    int s, d;
    if (e < E) { s = esrc[e]; d = edst[e]; } else { s = e - E; d = s; }
    int b = mapB[d];
    if (b < 0 || b >= capB) return;
    int slot = atomicAdd(&deg1[b], 1);
    if (slot < BINW) e1bin[b * BINW + slot] = s;
    int old = atomicCAS(&mapC[s], -1, -2);
    if (old == -1) {
        int idx = atomicAdd(&cnt[1], 1);
        if (idx < capC) listC[idx] = s;
        mapC[s] = idx;
    }
}

// ------------------------------------------------------------------
// Gather x rows (listC) -> compact bf16 Abf [capC][768]; extra block
// computes pre-clamped listBinC (B-row -> C-row).
// ------------------------------------------------------------------
__global__ void k_gatherA(const float* __restrict__ x,
                          const int* __restrict__ listC, const int* __restrict__ listB,
                          const int* __restrict__ mapC, const int* __restrict__ cnt,
                          u16* __restrict__ Abf, int* __restrict__ listBinC,
                          int capB, int capC)
{
    int bid = blockIdx.x;
    int t = threadIdx.x;
    if (bid == capC) {
        int nB = cnt[0]; if (nB > capB) nB = capB;
        for (int i = t; i < capB; i += 192) {
            int v = 0;
            if (i < nB) {
                v = mapC[listB[i]];
                if (v < 0) v = 0;
                if (v >= capC) v = capC - 1;
            }
            listBinC[i] = v;
        }
        return;
    }
    int nC = cnt[1]; if (nC > capC) nC = capC;
    if (bid >= nC) return;
    int g = listC[bid];
    float4 v = *reinterpret_cast<const float4*>(x + (size_t)g * 768 + t * 4);
    uint2 o;
    o.x = (u32)f2bf(v.x) | ((u32)f2bf(v.y) << 16);
    o.y = (u32)f2bf(v.z) | ((u32)f2bf(v.w) << 16);
    *reinterpret_cast<uint2*>(Abf + (size_t)bid * 768 + t * 4) = o;
}

// ------------------------------------------------------------------
// Round-4-proven MFMA GEMM tile (register-light, LDS double staging):
// C[r, n] = sum_{k in [k0,k0+kchunk)} A[g(r), k] * W[k, nColOff+n] (+bias)
// A: bf16 compact. W: f32 k-major, transposed+converted during LDS staging.
// 64x64 tile, 4 waves (2x2), BK=64, 16x16x32 bf16 MFMA, XOR swizzle.
// mode: 0 = f32 store (no bias), 2 = bf16 store (+bias).
// ------------------------------------------------------------------
__device__ __forceinline__
void gemm_tile(const u16* __restrict__ A, int lda,
               const int* __restrict__ gather,
               const float* __restrict__ W, int ldw, int nColOff,
               const float* __restrict__ bias,
               void* __restrict__ Cout, int ldc, int mode,
               int M, int bx, int by, int k0, int kchunk,
               u16* __restrict__ As, u16* __restrict__ Bs)
{
    int m0 = by * 64;
    if (m0 >= M) return;
    int n0 = bx * 64;
    int t = threadIdx.x;
    int lane = t & 63, wave = t >> 6;
    int wr = wave >> 1, wc = wave & 1;
    int lrow = lane & 15, lhi = lane >> 4;

    // A staging: thread covers rows t>>3 and 32+(t>>3), 8 k each
    int chunk = t & 7;
    int rowp[2], aRow[2], wIdx[2];
    #pragma unroll
    for (int p = 0; p < 2; ++p) {
        rowp[p] = p * 32 + (t >> 3);
        int ar = m0 + rowp[p]; if (ar >= M) ar = M - 1;
        aRow[p] = gather ? gather[ar] : ar;
        wIdx[p] = rowp[p] * 64 + ((chunk ^ (rowp[p] & 7)) << 3);
    }
    // B staging: thread covers k = p*16 + (t>>4), n = (t&15)*4 .. +3
    int bk = t >> 4;
    int bn = (t & 15) << 2;

    int aIdx[2][2], bIdx[2][2];
    #pragma unroll
    for (int mi = 0; mi < 2; ++mi)
        #pragma unroll
        for (int ks = 0; ks < 2; ++ks) {
            int ra = wr * 32 + mi * 16 + lrow;
            aIdx[mi][ks] = ra * 64 + ((((ks << 2) | lhi) ^ (ra & 7)) << 3);
            int rb = wc * 32 + mi * 16 + lrow;
            bIdx[mi][ks] = rb * 64 + ((((ks << 2) | lhi) ^ (rb & 7)) << 3);
        }

    f32x4 acc[2][2];
    #pragma unroll
    for (int i = 0; i < 2; ++i)
        #pragma unroll
        for (int j = 0; j < 2; ++j)
            acc[i][j] = (f32x4){0.f, 0.f, 0.f, 0.f};

    for (int kt = 0; kt < kchunk; kt += 64) {
        int kb = k0 + kt;
        #pragma unroll
        for (int p = 0; p < 2; ++p) {
            uint4 av = *reinterpret_cast<const uint4*>(
                A + (size_t)aRow[p] * lda + kb + chunk * 8);
            *reinterpret_cast<uint4*>(&As[wIdx[p]]) = av;
        }
        #pragma unroll
        for (int p = 0; p < 4; ++p) {
            int kk = p * 16 + bk;
            const float* wp = W + (size_t)(kb + kk) * ldw + nColOff + n0 + bn;
            float4 wv = *reinterpret_cast<const float4*>(wp);
            float wa[4] = {wv.x, wv.y, wv.z, wv.w};
            #pragma unroll
            for (int j = 0; j < 4; ++j) {
                int n = bn + j;
                int pc = (kk & 7) | ((((kk >> 3) & 7) ^ (n & 7)) << 3);
                Bs[n * 64 + pc] = f2bf(wa[j]);
            }
        }
        __syncthreads();
        #pragma unroll
        for (int ks = 0; ks < 2; ++ks) {
            bf16x8 a0 = *reinterpret_cast<const bf16x8*>(&As[aIdx[0][ks]]);
            bf16x8 a1 = *reinterpret_cast<const bf16x8*>(&As[aIdx[1][ks]]);
            bf16x8 b0 = *reinterpret_cast<const bf16x8*>(&Bs[bIdx[0][ks]]);
            bf16x8 b1 = *reinterpret_cast<const bf16x8*>(&Bs[bIdx[1][ks]]);
            acc[0][0] = __builtin_amdgcn_mfma_f32_16x16x32_bf16(a0, b0, acc[0][0], 0, 0, 0);
            acc[0][1] = __builtin_amdgcn_mfma_f32_16x16x32_bf16(a0, b1, acc[0][1], 0, 0, 0);
            acc[1][0] = __builtin_amdgcn_mfma_f32_16x16x32_bf16(a1, b0, acc[1][0], 0, 0, 0);
            acc[1][1] = __builtin_amdgcn_mfma_f32_16x16x32_bf16(a1, b1, acc[1][1], 0, 0, 0);
        }
        __syncthreads();
    }

    #pragma unroll
    for (int mi = 0; mi < 2; ++mi)
        #pragma unroll
        for (int ni = 0; ni < 2; ++ni) {
            int gc = n0 + wc * 32 + ni * 16 + lrow;
            float bv = (mode == 2) ? bias[gc] : 0.f;
            #pragma unroll
            for (int j = 0; j < 4; ++j) {
                int gr = m0 + wr * 32 + mi * 16 + lhi * 4 + j;
                if (gr < M) {
                    float v = acc[mi][ni][j] + bv;
                    if (mode == 2) ((u16*)Cout)[(size_t)gr * ldc + gc] = f2bf(v);
                    else           ((float*)Cout)[(size_t)gr * ldc + gc] = v;
                }
            }
        }
}

// Layer-1: XL1' = bf16(Abf@Wl1 + bl1), XR1' = bf16(Abf[listBinC]@Wr1 + br1)
__global__ __launch_bounds__(256)
void k_gemm1(const u16* __restrict__ Abf, const int* __restrict__ listBinC,
             const float* __restrict__ Wl1, const float* __restrict__ Wr1,
             const float* __restrict__ bl1, const float* __restrict__ br1,
             u16* __restrict__ XL1, u16* __restrict__ XR1,
             const int* __restrict__ cnt, int capC, int capB)
{
    __shared__ __align__(16) u16 As[64 * 64];
    __shared__ __align__(16) u16 Bs[64 * 64];
    int partA = 48 * (capC / 64);
    int bid = blockIdx.x;
    if (bid < partA) {
        int nC = cnt[1]; if (nC > capC) nC = capC;
        gemm_tile(Abf, 768, nullptr, Wl1, 3072, 0, bl1, XL1, 3072, 2,
                  nC, bid % 48, bid / 48, 0, 768, As, Bs);
    } else {
        bid -= partA;
        int nB = cnt[0]; if (nB > capB) nB = capB;
        gemm_tile(Abf, 768, listBinC, Wr1, 3072, 0, br1, XR1, 3072, 2,
                  nB, bid % 48, bid / 48, 0, 768, As, Bs);
    }
}

// Layer-2: XLR2part[z] = H1bf[:, zK:(z+1)K] @ [Wl2|Wr2][zK:(z+1)K, :]
// f32 store into partial buffer z (no atomics, no zero-init needed).
__global__ __launch_bounds__(256)
void k_gemm2(const u16* __restrict__ H1bf,
             const float* __restrict__ Wl2, const float* __restrict__ Wr2,
             float* __restrict__ XLR2,
             const int* __restrict__ cnt, int capB)
{
    __shared__ __align__(16) u16 As[64 * 64];
    __shared__ __align__(16) u16 Bs[64 * 64];
    int nB = cnt[0]; if (nB > capB) nB = capB;
    int z = blockIdx.z;
    int n0 = blockIdx.x * 64;              // global col in [0,1536)
    bool hi = n0 >= 768;
    const float* W = hi ? Wr2 : Wl2;
    int nColOff = hi ? -768 : 0;
    const int kchunk = 3072 / NZ2;
    float* Cp = XLR2 + (size_t)z * capB * 1536;
    gemm_tile(H1bf, 3072, nullptr, W, 768, nColOff, nullptr, Cp, 1536, 0,
              nB, blockIdx.x, blockIdx.y, z * kchunk, kchunk, As, Bs);
}

// ------------------------------------------------------------------
// Fused layer-1 edge phase: one block per B node, 4 waves = 4 heads.
// ------------------------------------------------------------------
__global__ __launch_bounds__(256)
void k_fused1(const u16* __restrict__ XL1, const u16* __restrict__ XR1,
              const float* __restrict__ att1, const float* __restrict__ bias1,
              const int* __restrict__ mapC,
              const int* __restrict__ deg1, const int* __restrict__ e1bin,
              u16* __restrict__ H1bf,
              const int* __restrict__ cnt, int capB, int capC)
{
    __shared__ int sIdx[BINW];
    int b = blockIdx.x;
    int nB = cnt[0]; if (nB > capB) nB = capB;
    if (b >= nB) return;
    int t = threadIdx.x;
    int n = deg1[b]; if (n > BINW) n = BINW;
    if (t < n) {
        int c = mapC[e1bin[b * BINW + t]];
        if (c < 0) c = 0; if (c >= capC) c = capC - 1;
        sIdx[t] = c;
    }
    __syncthreads();

    int base = t * 12;
    float xr[12], av[12];
    {
        const u16* p = XR1 + (size_t)b * 3072 + base;
        uint2 q0 = *reinterpret_cast<const uint2*>(p);
        uint2 q1 = *reinterpret_cast<const uint2*>(p + 4);
        uint2 q2 = *reinterpret_cast<const uint2*>(p + 8);
        u32 w[6] = {q0.x, q0.y, q1.x, q1.y, q2.x, q2.y};
        #pragma unroll
        for (int j = 0; j < 6; ++j) {
            xr[2*j]   = bf2f((u16)(w[j] & 0xFFFF));
            xr[2*j+1] = bf2f((u16)(w[j] >> 16));
        }
        float4 a0 = *reinterpret_cast<const float4*>(att1 + base);
        float4 a1 = *reinterpret_cast<const float4*>(att1 + base + 4);
        float4 a2 = *reinterpret_cast<const float4*>(att1 + base + 8);
        av[0]=a0.x; av[1]=a0.y; av[2]=a0.z; av[3]=a0.w;
        av[4]=a1.x; av[5]=a1.y; av[6]=a1.z; av[7]=a1.w;
        av[8]=a2.x; av[9]=a2.y; av[10]=a2.z; av[11]=a2.w;
    }

    float acc[12];
    #pragma unroll
    for (int j = 0; j < 12; ++j) acc[j] = 0.f;
    float sumex = 0.f;

    uint2 q0, q1, q2;
    if (n > 0) {
        const u16* p = XL1 + (size_t)sIdx[0] * 3072 + base;
        q0 = *reinterpret_cast<const uint2*>(p);
        q1 = *reinterpret_cast<const uint2*>(p + 4);
        q2 = *reinterpret_cast<const uint2*>(p + 8);
    }
    for (int i = 0; i < n; ++i) {
        uint2 r0 = q0, r1 = q1, r2 = q2;
        if (i + 1 < n) {
            const u16* p = XL1 + (size_t)sIdx[i + 1] * 3072 + base;
            q0 = *reinterpret_cast<const uint2*>(p);
            q1 = *reinterpret_cast<const uint2*>(p + 4);
            q2 = *reinterpret_cast<const uint2*>(p + 8);
        }
        float xl[12];
        u32 w[6] = {r0.x, r0.y, r1.x, r1.y, r2.x, r2.y};
        #pragma unroll
        for (int j = 0; j < 6; ++j) {
            xl[2*j]   = bf2f((u16)(w[j] & 0xFFFF));
            xl[2*j+1] = bf2f((u16)(w[j] >> 16));
        }
        float pa = 0.f;
        #pragma unroll
        for (int j = 0; j < 12; ++j)
            pa = fmaf(av[j], lrelu(xl[j] + xr[j]), pa);
        #pragma unroll
        for (int off = 32; off > 0; off >>= 1) pa += __shfl_xor(pa, off);
        float ex = expf(pa);
        sumex += ex;
        #pragma unroll
        for (int j = 0; j < 12; ++j) acc[j] = fmaf(ex, xl[j], acc[j]);
    }

    float inv = 1.f / (sumex + 1e-16f);
    u32 o[6];
    #pragma unroll
    for (int j = 0; j < 6; ++j) {
        float v0 = acc[2*j]   * inv + bias1[base + 2*j];
        float v1 = acc[2*j+1] * inv + bias1[base + 2*j+1];
        v0 = v0 > 0.f ? v0 : 0.f;
        v1 = v1 > 0.f ? v1 : 0.f;
        o[j] = (u32)f2bf(v0) | ((u32)f2bf(v1) << 16);
    }
    u16* q = H1bf + (size_t)b * 3072 + base;
    uint2 s0; s0.x = o[0]; s0.y = o[1];
    uint2 s1; s1.x = o[2]; s1.y = o[3];
    uint2 s2; s2.x = o[4]; s2.y = o[5];
    *reinterpret_cast<uint2*>(q)     = s0;
    *reinterpret_cast<uint2*>(q + 4) = s1;
    *reinterpret_cast<uint2*>(q + 8) = s2;
}

// ------------------------------------------------------------------
// Fused layer-2 edge phase: one block per pathology node, 4 waves split
// edges, LDS combine. Sums NZ2 K-partials + folded biases. Writes d_out.
// ------------------------------------------------------------------
__global__ __launch_bounds__(256)
void k_fused2(const float* __restrict__ XLR2,
              const float* __restrict__ att2, const float* __restrict__ bias2,
              const float* __restrict__ bl2, const float* __restrict__ br2,
              const int* __restrict__ mapB,
              const int* __restrict__ deg2, const int* __restrict__ e2bin,
              float* __restrict__ out, int capB)
{
    __shared__ int sIdx[BINW];
    __shared__ float sAcc[4][768];
    __shared__ float sSum[4];
    const size_t PART = (size_t)capB * 1536;
    int a = blockIdx.x;
    int t = threadIdx.x;
    int wv = t >> 6, lane = t & 63;
    int n = deg2[a]; if (n > BINW) n = BINW;
    if (t < n) {
        int bs = mapB[e2bin[a * BINW + t]];
        if (bs < 0) bs = 0; if (bs >= capB) bs = capB - 1;
        sIdx[t] = bs;
    }
    __syncthreads();

    int base = lane * 12;
    int bd = mapB[a];
    if (bd < 0) bd = 0; if (bd >= capB) bd = capB - 1;

    float xr[12], av[12], blv[12];
    {
        const float* p = XLR2 + (size_t)bd * 1536 + 768 + base;
        #pragma unroll
        for (int j = 0; j < 12; ++j) xr[j] = br2[base + j];
        for (int z = 0; z < NZ2; ++z)
            #pragma unroll
            for (int j = 0; j < 12; ++j) xr[j] += p[z * PART + j];
        #pragma unroll
        for (int j = 0; j < 12; ++j) { av[j] = att2[base + j]; blv[j] = bl2[base + j]; }
    }

    float acc[12];
    #pragma unroll
    for (int j = 0; j < 12; ++j) acc[j] = 0.f;
    float sumex = 0.f;

    for (int i = wv; i < n; i += 4) {
        int bs = sIdx[i];
        const float* p = XLR2 + (size_t)bs * 1536 + base;
        float xl[12];
        #pragma unroll
        for (int j = 0; j < 12; ++j) xl[j] = blv[j];
        for (int z = 0; z < NZ2; ++z)
            #pragma unroll
            for (int j = 0; j < 12; ++j) xl[j] += p[z * PART + j];
        float pa = 0.f;
        #pragma unroll
        for (int j = 0; j < 12; ++j)
            pa = fmaf(av[j], lrelu(xl[j] + xr[j]), pa);
        #pragma unroll
        for (int off = 32; off > 0; off >>= 1) pa += __shfl_xor(pa, off);
        float ex = expf(pa);
        sumex += ex;
        #pragma unroll
        for (int j = 0; j < 12; ++j) acc[j] = fmaf(ex, xl[j], acc[j]);
    }

    if (lane == 0) sSum[wv] = sumex;
    #pragma unroll
    for (int j = 0; j < 12; ++j) sAcc[wv][base + j] = acc[j];
    __syncthreads();

    float tot = sSum[0] + sSum[1] + sSum[2] + sSum[3];
    float inv = 1.f / (tot + 1e-16f);
    for (int c = t; c < 768; c += 256) {
        float s = sAcc[0][c] + sAcc[1][c] + sAcc[2][c] + sAcc[3][c];
        out[(size_t)a * 768 + c] = s * inv + bias2[c];
    }
}

// ------------------------------------------------------------------
// Host side
// ------------------------------------------------------------------
struct Lay {
    size_t mapB, mapC;
    size_t zbase, zbytes;
    size_t cnt, deg2, deg1;
    size_t listB, listC, listBinC, e1bin, e2bin;
    size_t Abf, XL1, XR1, H1bf, XLR2;
    size_t total;
};

static Lay makeLayout(int Nn, int cB, int cC)
{
    Lay L{};
    size_t off = 0;
    auto take = [&](size_t bytes) { size_t o = (off + 255) & ~(size_t)255; off = o + bytes; return o; };
    L.mapB = take((size_t)2 * Nn * 4);
    L.mapC = L.mapB + (size_t)Nn * 4;
    size_t zo = 0;
    size_t cntO  = zo; zo += 64;
    size_t deg2O = zo; zo += 64 * 4;
    size_t deg1O = zo; zo += (size_t)cB * 4;
    L.zbase = take(zo); L.zbytes = zo;
    L.cnt  = L.zbase + cntO;
    L.deg2 = L.zbase + deg2O;
    L.deg1 = L.zbase + deg1O;
    L.listB    = take((size_t)cB * 4);
    L.listC    = take((size_t)cC * 4);
    L.listBinC = take((size_t)cB * 4);
    L.e1bin = take((size_t)cB * BINW * 4);
    L.e2bin = take((size_t)16 * BINW * 4);
    L.Abf  = take((size_t)cC * 768 * 2);
    L.XL1  = take((size_t)cC * 3072 * 2);
    L.XR1  = take((size_t)cB * 3072 * 2);
    L.H1bf = take((size_t)cB * 3072 * 2);
    L.XLR2 = take((size_t)NZ2 * cB * 1536 * 4);
    L.total = off;
    return L;
}

extern "C" void kernel_launch(void* const* d_in, const int* in_sizes, int n_in,
                              void* d_out, int out_size, void* d_ws, size_t ws_size,
                              hipStream_t stream)
{
    const float* x     = (const float*)d_in[0];
    const int*   ei    = (const int*)  d_in[1];
    const float* Wl1   = (const float*)d_in[2];
    const float* bl1   = (const float*)d_in[3];
    const float* Wr1   = (const float*)d_in[4];
    const float* br1   = (const float*)d_in[5];
    const float* att1  = (const float*)d_in[6];
    const float* bias1 = (const float*)d_in[7];
    const float* Wl2   = (const float*)d_in[8];
    const float* bl2   = (const float*)d_in[9];
    const float* Wr2   = (const float*)d_in[10];
    const float* br2   = (const float*)d_in[11];
    const float* att2  = (const float*)d_in[12];
    const float* bias2 = (const float*)d_in[13];
    float* out = (float*)d_out;

    int Nn = in_sizes[0] / 768;
    int E  = in_sizes[1] / 2;
    const int* esrc = ei;
    const int* edst = ei + E;
    int ET = E + Nn;

    // expected actual sizes: B~99, C~650
    static const int tiers[2][2] = { {256, 1024}, {128, 768} };
    int capB = tiers[1][0], capC = tiers[1][1];
    Lay L = makeLayout(Nn, capB, capC);
    for (int t = 0; t < 2; ++t) {
        Lay cand = makeLayout(Nn, tiers[t][0], tiers[t][1]);
        if (cand.total <= ws_size) { capB = tiers[t][0]; capC = tiers[t][1]; L = cand; break; }
    }

    char* ws = (char*)d_ws;
    int*   mapB     = (int*)  (ws + L.mapB);
    int*   mapC     = (int*)  (ws + L.mapC);
    int*   cnt      = (int*)  (ws + L.cnt);
    int*   deg2     = (int*)  (ws + L.deg2);
    int*   deg1     = (int*)  (ws + L.deg1);
    int*   listB    = (int*)  (ws + L.listB);
    int*   listC    = (int*)  (ws + L.listC);
    int*   listBinC = (int*)  (ws + L.listBinC);
    int*   e1bin    = (int*)  (ws + L.e1bin);
    int*   e2bin    = (int*)  (ws + L.e2bin);
    u16*   Abf      = (u16*)  (ws + L.Abf);
    u16*   XL1      = (u16*)  (ws + L.XL1);
    u16*   XR1      = (u16*)  (ws + L.XR1);
    u16*   H1bf     = (u16*)  (ws + L.H1bf);
    float* XLR2     = (float*)(ws + L.XLR2);

    k_init<<<256, 256, 0, stream>>>((int*)(ws + L.mapB), 2 * Nn,
                                    (u32*)(ws + L.zbase), (int)(L.zbytes / 4));

    int bgrid = (ET + 255) / 256;
    k_build2<<<bgrid, 256, 0, stream>>>(esrc, edst, E, Nn, mapB, listB, cnt,
                                        deg2, e2bin, capB);
    k_build1<<<bgrid, 256, 0, stream>>>(esrc, edst, E, Nn, mapB, mapC, listC, cnt,
                                        deg1, e1bin, capB, capC);

    k_gatherA<<<capC + 1, 192, 0, stream>>>(x, listC, listB, mapC, cnt,
                                            Abf, listBinC, capB, capC);

    int g1 = 48 * (capC / 64) + 48 * (capB / 64);
    k_gemm1<<<g1, 256, 0, stream>>>(Abf, listBinC, Wl1, Wr1, bl1, br1,
                                    XL1, XR1, cnt, capC, capB);

    k_fused1<<<capB, 256, 0, stream>>>(XL1, XR1, att1, bias1, mapC, deg1, e1bin,
                                       H1bf, cnt, capB, capC);

    k_gemm2<<<dim3(24, capB / 64, NZ2), 256, 0, stream>>>(H1bf, Wl2, Wr2, XLR2,
                                                          cnt, capB);

    k_fused2<<<N_PATH, 256, 0, stream>>>(XLR2, att2, bias2, bl2, br2, mapB,
                                         deg2, e2bin, out, capB);
}